// Round 19
// baseline (433.811 us; speedup 1.0000x reference)
//
#include <hip/hip_runtime.h>
#include <hip/hip_bf16.h>
#include <math.h>

typedef unsigned short u16;
typedef __attribute__((ext_vector_type(8))) short short8;   // 8 bf16 MFMA A/B frag
typedef __attribute__((ext_vector_type(4))) short short4v;  // 4 bf16 packed
typedef __attribute__((ext_vector_type(4))) float f32x4;    // MFMA C/D frag

#define MFMA(a,b,c) __builtin_amdgcn_mfma_f32_16x16x32_bf16(a,b,c,0,0,0)
#define DIM 192

__device__ __forceinline__ float bf2f(u16 u){ unsigned v=((unsigned)u)<<16; float f; __builtin_memcpy(&f,&v,4); return f; }
__device__ __forceinline__ u16 f2bf(float f){ unsigned v; __builtin_memcpy(&v,&f,4); v = v + 0x7fffu + ((v>>16)&1u); return (u16)(v>>16); }

__device__ __forceinline__ void gl_lds16(const u16* g, u16* l){
  __builtin_amdgcn_global_load_lds((const __attribute__((address_space(1))) unsigned int*)g,
                                   (__attribute__((address_space(3))) unsigned int*)l, 16, 0, 0);
}

// windowed row -> original token index (inverse of roll(-1,-3,-6) + partition)
__device__ __forceinline__ int win_to_tok(int r){
  int lon = r/9216; int rem = r - lon*9216;      // 9216 = 64*144
  int w = rem/144, n = rem - w*144;
  int ip=w>>4, il=w&15;
  int wp=n/72, t=n-wp*72, wl=t/12, ww=t-wl*12;
  int p=ip*2+wp, la=il*6+wl, lo=lon*12+ww;
  int p0=p+1;  if(p0>=8)   p0-=8;
  int la0=la+3; if(la0>=96) la0-=96;
  int lo0=lo+6; if(lo0>=180)lo0-=180;
  return (p0*96+la0)*180+lo0;
}

// ---------------- K2: merged preformat (4 ranged sub-kernels, one launch) ----------------
// blocks [0,432): qkv_w fp32[192][576] -> Wq bf16[576][192]
// blocks [432,576): proj_w fp32[192][192] -> Pw bf16[192][192]
// blocks [576,1152): fc1 -> W1f[hc 24][r 32][g 24][e 8], swizzle baked
// blocks [1152,1728): fc2 -> W2f[hc 24][r 192][g 4][e 8], swizzle baked
__global__ __launch_bounds__(256) void prep_kernel(
    const float* __restrict__ qkvw, u16* __restrict__ Wq,
    const float* __restrict__ projw, u16* __restrict__ Pw,
    const float* __restrict__ fc1w, u16* __restrict__ W1f,
    const float* __restrict__ fc2w, u16* __restrict__ W2f)
{
  int bid = blockIdx.x, tid = threadIdx.x;
  if (bid < 432) {
    int idx = bid*256 + tid;                    // 110592
    int k = idx / 576, n = idx - k*576;
    Wq[n*192 + k] = f2bf(qkvw[idx]);
  } else if (bid < 576) {
    int idx = (bid-432)*256 + tid;              // 36864
    int k = idx / 192, n = idx - k*192;
    Pw[n*192 + k] = f2bf(projw[idx]);
  } else if (bid < 1152) {
    int idx = (bid-576)*256 + tid;              // 147456
    int e = idx & 7, g3 = idx >> 3;
    int g = g3 % 24, r3 = g3 / 24;
    int r = r3 & 31, hc = r3 >> 5;
    int k = ((g ^ (r&7))<<3) + e;
    W1f[idx] = f2bf(fc1w[(size_t)k*768 + hc*32 + r]);
  } else {
    int idx = (bid-1152)*256 + tid;             // 147456
    int e = idx & 7, g3 = idx >> 3;
    int g = g3 & 3, r3 = g3 >> 2;
    int r = r3 % 192, hc = r3 / 192;
    int k = hc*32 + ((g ^ (r&3))<<3) + e;
    W2f[idx] = f2bf(fc2w[(size_t)k*192 + r]);
  }
}

// ---------------- K2c: expand earth bias+mask -> lane-packed Bexp ----------------
__global__ __launch_bounds__(256) void bias_expand_kernel(
    const float* __restrict__ eb, u16* __restrict__ B2)
{
  __shared__ int t1s[144], t2s[144], rgs[144];
  __shared__ float ebs[3312];
  int bid = blockIdx.x;           // bid = w*6 + h
  int w = bid / 6;
  int tid = threadIdx.x;
  if (tid < 144) {
    int n = tid;
    int wp=n/72, t=n-wp*72, wl=t/12, ww=t-wl*12;
    t1s[n] = wp*828 + wl*23 + ww;
    t2s[n] = 1656*wp + 138*wl - ww + 11;
    int ip = w>>4, il = w&15;
    int p = ip*2+wp, la = il*6+wl;
    int rp = (p<6)?0:((p<7)?1:2);
    int rl = (la<90)?0:((la<93)?1:2);
    rgs[n] = rp*3+rl;
  }
  for (int i = tid; i < 3312; i += 256) ebs[i] = eb[(size_t)i*384 + bid];
  __syncthreads();
  size_t ob = (size_t)bid*20736;
  for (int idx = tid; idx < 20736; idx += 256) {
    int i = idx & 3, lane = (idx>>2)&63, t = idx>>8;   // t = nt*9+mt
    int mt = t%9, nt = t/9;
    int n = nt*16 + (lane&15);
    int m = mt*16 + ((lane>>4)<<2) + i;
    float bv = ebs[t1s[n]+t2s[m]];
    bv += (rgs[n]==rgs[m]) ? 0.f : -100.f;
    B2[ob + idx] = f2bf(bv);
  }
}

// ---------------- K3: fused LN1 + QKV + earth attention per (lon,w,head) ----------------
#define SM_WS   0                  // 36864 B  (96*192*2)
#define SM_QS   36864              // 11520 B  (144*40*2)
#define SM_KS   48384              // 11520 B
#define SM_VS   59904              // 10752 B  (32*168*2)
#define SM_PS   0                  // 48384 B  overlays Ws+qs (time-multiplexed)
#define SMEM3   70656              // 2 blocks/CU

__global__ __launch_bounds__(576) void attn_kernel(
    const float* __restrict__ x,    // [138240][192] fp32 (token order)
    const float* __restrict__ n1g, const float* __restrict__ n1b,
    const u16* __restrict__ Wt,     // qkv_w_t bf16 [576][192]
    const float* __restrict__ qkvb, // [576]
    const u16* __restrict__ Bexp,   // lane-packed [384][9][9][64][4] bf16
    u16* __restrict__ O)            // windowed attn out bf16 [138240][192]
{
  extern __shared__ char smem[];
  u16* Ws = (u16*)(smem + SM_WS);
  u16* qs = (u16*)(smem + SM_QS);
  u16* ks_= (u16*)(smem + SM_KS);
  u16* vs = (u16*)(smem + SM_VS);
  u16* Ps = (u16*)(smem + SM_PS);

  int bid = blockIdx.x;
  int logical = (bid & 7)*720 + (bid >> 3);     // bijective XCD remap
  int lon = logical % 15;
  int wh  = logical / 15;
  int h = wh % 6, w = wh / 6;
  int tid = threadIdx.x, lane = tid & 63, wv = tid >> 6;

  { // stage per-head weight slice into swizzled Ws (granule g^(row&7))
    int rr = tid % 96, chunk = tid / 96;
    int mat = rr >> 5, c = rr & 31;
    const u16* s = Wt + (size_t)(mat*192 + h*32 + c)*192 + chunk*32;
    uint4 t0 = *(const uint4*)(s);
    uint4 t1 = *(const uint4*)(s+8);
    uint4 t2 = *(const uint4*)(s+16);
    uint4 t3 = *(const uint4*)(s+24);
    u16* d = Ws + rr*192;
    int r7 = rr & 7, g0 = chunk*4;
    *(uint4*)(d + ((g0  )^r7)*8) = t0;
    *(uint4*)(d + ((g0+1)^r7)*8) = t1;
    *(uint4*)(d + ((g0+2)^r7)*8) = t2;
    *(uint4*)(d + ((g0+3)^r7)*8) = t3;
  }
  if (tid < 512) { int c = tid>>4; vs[c*168 + 144 + (tid&15)] = 0; }

  size_t winbase = (size_t)(lon*64 + w)*144;
  int r0 = wv*16;
  int l15 = lane & 15, lg = lane >> 4;
  int sw7 = l15 & 7;

  // ---- fused LN1: load x row (fp32), one-pass stats, pack bf16 af frags ----
  // lane (l15,lg) owns row r0+l15, cols {k0*32+8lg .. +8}; 192-col reduce = 2 shfl_xor.
  short8 af[6];
  {
    int tok = win_to_tok((int)(winbase + r0 + l15));
    const float* xrow = x + (size_t)tok*DIM;
    float xv[48];
    float ssum = 0.f, qsum = 0.f;
    #pragma unroll
    for (int k0=0;k0<6;k0++){
      f32x4 a = *(const f32x4*)(xrow + k0*32 + 8*lg);
      f32x4 b = *(const f32x4*)(xrow + k0*32 + 8*lg + 4);
      #pragma unroll
      for (int e=0;e<4;e++){
        xv[k0*8+e]   = a[e]; ssum += a[e]; qsum += a[e]*a[e];
        xv[k0*8+4+e] = b[e]; ssum += b[e]; qsum += b[e]*b[e];
      }
    }
    ssum += __shfl_xor(ssum, 16); ssum += __shfl_xor(ssum, 32);
    qsum += __shfl_xor(qsum, 16); qsum += __shfl_xor(qsum, 32);
    float mean = ssum*(1.f/192.f);
    float rstd = rsqrtf(qsum*(1.f/192.f) - mean*mean + 1e-5f);
    #pragma unroll
    for (int k0=0;k0<6;k0++){
      f32x4 gg = *(const f32x4*)(n1g + k0*32 + 8*lg);
      f32x4 g2 = *(const f32x4*)(n1g + k0*32 + 8*lg + 4);
      f32x4 bb = *(const f32x4*)(n1b + k0*32 + 8*lg);
      f32x4 b2 = *(const f32x4*)(n1b + k0*32 + 8*lg + 4);
      short8 pk;
      #pragma unroll
      for (int e=0;e<4;e++){
        pk[e]   = (short)f2bf((xv[k0*8+e]  -mean)*rstd*gg[e] + bb[e]);
        pk[4+e] = (short)f2bf((xv[k0*8+4+e]-mean)*rstd*g2[e] + b2[e]);
      }
      af[k0] = pk;
    }
  }
  __syncthreads();   // Ws staged (barrier moved after LN so x-load latency hides here)

  const float qscale = 0.17677669529663687f;

  #pragma unroll
  for (int mt=0; mt<2; mt++) {
    f32x4 acc = {0.f,0.f,0.f,0.f};
    const u16* wrow = Ws + (mt*16 + l15)*192;
    #pragma unroll
    for (int k0=0;k0<6;k0++) acc = MFMA(*(const short8*)(wrow + ((k0*4+lg)^sw7)*8), af[k0], acc);
    short4v pk;
    #pragma unroll
    for (int i=0;i<4;i++) pk[i] = (short)f2bf((acc[i] + qkvb[h*32 + mt*16 + 4*lg + i])*qscale);
    *(short4v*)(qs + (r0 + l15)*40 + mt*16 + 4*lg) = pk;
  }
  #pragma unroll
  for (int mt=0; mt<2; mt++) {
    f32x4 acc = {0.f,0.f,0.f,0.f};
    const u16* wrow = Ws + (32 + mt*16 + l15)*192;
    #pragma unroll
    for (int k0=0;k0<6;k0++) acc = MFMA(*(const short8*)(wrow + ((k0*4+lg)^sw7)*8), af[k0], acc);
    short4v pk;
    #pragma unroll
    for (int i=0;i<4;i++) pk[i] = (short)f2bf(acc[i] + qkvb[192 + h*32 + mt*16 + 4*lg + i]);
    *(short4v*)(ks_ + (r0 + l15)*40 + mt*16 + 4*lg) = pk;
  }
  #pragma unroll
  for (int ct=0; ct<2; ct++) {
    f32x4 acc = {0.f,0.f,0.f,0.f};
    const u16* wrow = Ws + (64 + ct*16 + l15)*192;
    #pragma unroll
    for (int k0=0;k0<6;k0++) acc = MFMA(af[k0], *(const short8*)(wrow + ((k0*4+lg)^sw7)*8), acc);
    float bias = qkvb[384 + h*32 + ct*16 + l15];
    short4v pk;
    #pragma unroll
    for (int i=0;i<4;i++) pk[i] = (short)f2bf(acc[i] + bias);
    *(short4v*)(vs + (ct*16 + l15)*168 + r0 + 4*lg) = pk;
  }
  __syncthreads();

  short8 bq = *(const short8*)(qs + (r0 + l15)*40 + 8*lg);
  f32x4 sa[9];
  #pragma unroll
  for (int mt=0; mt<9; mt++) {
    f32x4 z = {0.f,0.f,0.f,0.f};
    sa[mt] = MFMA(*(const short8*)(ks_ + (mt*16 + l15)*40 + 8*lg), bq, z);
  }
  __syncthreads();

  {
    const u16* bb = Bexp + (((size_t)wh*9 + wv)*9)*256 + lane*4;
    #pragma unroll
    for (int mt=0; mt<9; mt++) {
      short4v pk = *(const short4v*)(bb + mt*256);
      #pragma unroll
      for (int i=0;i<4;i++) sa[mt][i] += bf2f((u16)pk[i]);
    }
  }
  float rsum = 0.f;
  #pragma unroll
  for (int mt=0; mt<9; mt++)
    #pragma unroll
    for (int i=0;i<4;i++) { float e = __expf(sa[mt][i]); sa[mt][i] = e; rsum += e; }
  rsum += __shfl_xor(rsum, 16);
  rsum += __shfl_xor(rsum, 32);
  float rinv = 1.f / rsum;
  #pragma unroll
  for (int mt=0; mt<9; mt++) {
    short4v pk;
    #pragma unroll
    for (int i=0;i<4;i++) pk[i] = (short)f2bf(sa[mt][i]);
    *(short4v*)(Ps + (r0 + l15)*168 + mt*16 + 4*lg) = pk;
  }
  {
    short4v z = {0,0,0,0};
    *(short4v*)(Ps + (r0 + l15)*168 + 144 + 4*lg) = z;
  }

  #pragma unroll
  for (int ct2=0; ct2<2; ct2++) {
    f32x4 acc = {0.f,0.f,0.f,0.f};
    const u16* vr = vs + (ct2*16 + l15)*168 + 8*lg;
    const u16* pr = Ps + (r0 + l15)*168 + 8*lg;
    #pragma unroll
    for (int k0=0;k0<5;k0++) acc = MFMA(*(const short8*)(vr + 32*k0), *(const short8*)(pr + 32*k0), acc);
    short4v pk;
    #pragma unroll
    for (int i=0;i<4;i++) pk[i] = (short)f2bf(acc[i]*rinv);
    *(short4v*)(O + (winbase + r0 + l15)*DIM + h*32 + ct2*16 + 4*lg) = pk;
  }
}

// ---------------- K4: fused tail (R14 config) -- proj+LN2+MLP, fc1/fc2 pipelined ----------
#define SMEMF 74240
__global__ __launch_bounds__(512, 4) void fused_tail_kernel(
    u16* __restrict__ AT,          // in: attn out (windowed); scratch: x2 bf16
    const u16* __restrict__ Pw,    // proj_w_t bf16 [192][192]
    const float* __restrict__ pb, const float* __restrict__ x,
    const float* __restrict__ n2g, const float* __restrict__ n2b,
    const u16* __restrict__ W1f,  // [24][32][24][8]
    const float* __restrict__ b1,
    const u16* __restrict__ W2f,  // [24][192][4][8]
    const float* __restrict__ b2,
    float* __restrict__ out)
{
  extern __shared__ char smem[];
  u16* Pws  = (u16*)smem;                 // proj phase
  u16* Ys   = (u16*)smem;                 // handoff phase (overlay)
  u16* W1b0 = (u16*)smem;                 // mlp phase (overlay)
  u16* W1b1 = (u16*)(smem + 12288);
  u16* W2b0 = (u16*)(smem + 24576);
  u16* W2b1 = (u16*)(smem + 36864);
  u16* HsA  = (u16*)(smem + 49152);
  u16* HsB  = (u16*)(smem + 59392);
  int* tokmap = (int*)(smem + 73728);
  int tid = threadIdx.x;
  size_t rbase = (size_t)blockIdx.x*128;
  int lane = tid&63, wv = tid>>6, r0 = wv*16;
  int l15 = lane&15, lg = lane>>4;

  // ---- stage proj weights (swizzled) + tokmap ----
  #pragma unroll
  for (int j=0;j<9;j++){
    int g = j*512 + tid;
    int row = g/24, jj = g - row*24;
    uint4 t = *(const uint4*)(Pw + (size_t)row*192 + jj*8);
    *(uint4*)(Pws + row*192 + ((jj ^ (row&7))*8)) = t;
  }
  if (tid < 128) tokmap[tid] = win_to_tok((int)rbase + tid);
  __syncthreads();

  // ---- proj MFMA ----
  short8 af[6];
  {
    const u16* arow = AT + (rbase + r0 + l15)*DIM + 8*lg;
    #pragma unroll
    for (int k0=0;k0<6;k0++) af[k0] = *(const short8*)(arow + k0*32);
  }
  f32x4 acc[12];
  #pragma unroll
  for (int ct=0; ct<12; ct++) {
    f32x4 a = {0.f,0.f,0.f,0.f};
    const u16* wr = Pws + (ct*16+l15)*192;
    #pragma unroll
    for (int k0=0;k0<6;k0++) a = MFMA(af[k0], *(const short8*)(wr + (((k0*4+lg)^(l15&7))*8)), a);
    acc[ct] = a;
  }
  int toks[4];
  #pragma unroll
  for (int i=0;i<4;i++) toks[i] = tokmap[r0 + 4*lg + i];

  // ---- x2 = x + proj + pb; park bf16 in AT ----
  #pragma unroll
  for (int ct=0; ct<12; ct++) {
    int col = ct*16+l15;
    float bias = pb[col];
    #pragma unroll
    for (int i=0;i<4;i++){
      float v = x[(size_t)toks[i]*DIM + col] + acc[ct][i] + bias;
      acc[ct][i] = v;
      AT[(rbase + r0 + 4*lg + i)*DIM + col] = f2bf(v);
    }
  }
  // ---- LN2 ----
  float s[4] = {0,0,0,0};
  #pragma unroll
  for (int ct=0; ct<12; ct++) for (int i=0;i<4;i++) s[i] += acc[ct][i];
  #pragma unroll
  for (int i=0;i<4;i++){ for (int m=1;m<16;m<<=1) s[i] += __shfl_xor(s[i], m, 16); s[i] *= (1.f/192.f); }
  float q[4] = {0,0,0,0};
  #pragma unroll
  for (int ct=0; ct<12; ct++) for (int i=0;i<4;i++){ float d = acc[ct][i]-s[i]; q[i] += d*d; }
  #pragma unroll
  for (int i=0;i<4;i++){ for (int m=1;m<16;m<<=1) q[i] += __shfl_xor(q[i], m, 16); q[i] = rsqrtf(q[i]*(1.f/192.f)+1e-5f); }

  __syncthreads();    // all Pws reads done -> Ys overlay safe
  #pragma unroll
  for (int ct=0; ct<12; ct++) {
    int col = ct*16+l15;
    float gg = n2g[col], bb = n2b[col];
    #pragma unroll
    for (int i=0;i<4;i++)
      Ys[(r0 + 4*lg + i)*200 + col] = f2bf((acc[ct][i]-s[i])*q[i]*gg + bb);
  }
  #pragma unroll
  for (int k0=0;k0<6;k0++) af[k0] = *(const short8*)(Ys + (r0+l15)*200 + k0*32 + 8*lg);
  __syncthreads();    // all Ys reads done -> ring overlay safe

  // ---- stage W1(0), W2(0), W1(1) ----
  {
    gl_lds16(W1f + (size_t)tid*8, W1b0 + tid*8);
    if (tid < 256) gl_lds16(W1f + (size_t)(512+tid)*8, W1b0 + (512+tid)*8);
    gl_lds16(W2f + (size_t)tid*8, W2b0 + tid*8);
    if (tid < 256) gl_lds16(W2f + (size_t)(512+tid)*8, W2b0 + (512+tid)*8);
    const u16* s1 = W1f + 6144;
    gl_lds16(s1 + (size_t)tid*8, W1b1 + tid*8);
    if (tid < 256) gl_lds16(s1 + (size_t)(512+tid)*8, W1b1 + (512+tid)*8);
  }
  __syncthreads();

  f32x4 acc2[12];
  #pragma unroll
  for (int i=0;i<12;i++) acc2[i] = (f32x4){0.f,0.f,0.f,0.f};

  const float GA = -1.5957691216057307f;   // -2*0.7978845608
  const float GB = -0.07135481627272283f;  // -2*0.0356774081

  // prologue compute: fc1(0) -> HsA
  #pragma unroll
  for (int ct=0; ct<2; ct++) {
    f32x4 a1 = {0.f,0.f,0.f,0.f};
    const u16* wr = W1b0 + (ct*16+l15)*192;
    #pragma unroll
    for (int k0=0;k0<6;k0++) a1 = MFMA(af[k0], *(const short8*)(wr + (((k0*4+lg)^(l15&7))*8)), a1);
    float bb = b1[ct*16 + l15];
    #pragma unroll
    for (int i=0;i<4;i++){
      float v = a1[i] + bb;
      float t = v*v;
      float m = fmaf(t, GB, GA);
      float e = __expf(v*m);
      HsA[(r0 + 4*lg + i)*40 + ct*16 + l15] = f2bf(v*__builtin_amdgcn_rcpf(1.f + e));
    }
  }
  __syncthreads();    // all waves past fc1(0): W1b0 free for restage

  for (int hc=0; hc<24; hc++) {
    u16* HsCur = (hc&1) ? HsB : HsA;
    u16* HsNxt = (hc&1) ? HsA : HsB;
    u16* W2cur = (hc&1) ? W2b1 : W2b0;
    u16* W1nxt = (hc&1) ? W1b0 : W1b1;
    // issue prefetches into buffers freed by the previous barrier
    if (hc+2 < 24) {
      const u16* s1 = W1f + (size_t)(hc+2)*6144;
      u16* d1 = (hc&1) ? W1b1 : W1b0;
      gl_lds16(s1 + (size_t)tid*8, d1 + tid*8);
      if (tid < 256) gl_lds16(s1 + (size_t)(512+tid)*8, d1 + (512+tid)*8);
    }
    if (hc+1 < 24) {
      const u16* s2 = W2f + (size_t)(hc+1)*6144;
      u16* d2 = (hc&1) ? W2b0 : W2b1;
      gl_lds16(s2 + (size_t)tid*8, d2 + tid*8);
      if (tid < 256) gl_lds16(s2 + (size_t)(512+tid)*8, d2 + (512+tid)*8);
    }
    // fc2(hc): A = HsCur own rows, B = W2cur
    {
      short8 ah = *(const short8*)(HsCur + (r0+l15)*40 + 8*lg);
      #pragma unroll
      for (int ct2=0; ct2<12; ct2++) {
        const u16* wr2 = W2cur + (ct2*16+l15)*32 + ((lg ^ (l15&3))*8);
        acc2[ct2] = MFMA(ah, *(const short8*)(wr2), acc2[ct2]);
      }
    }
    // fc1(hc+1): B = W1nxt -> HsNxt (wave-private rows)
    if (hc+1 < 24) {
      #pragma unroll
      for (int ct=0; ct<2; ct++) {
        f32x4 a1 = {0.f,0.f,0.f,0.f};
        const u16* wr = W1nxt + (ct*16+l15)*192;
        #pragma unroll
        for (int k0=0;k0<6;k0++) a1 = MFMA(af[k0], *(const short8*)(wr + (((k0*4+lg)^(l15&7))*8)), a1);
        float bb = b1[(hc+1)*32 + ct*16 + l15];
        #pragma unroll
        for (int i=0;i<4;i++){
          float v = a1[i] + bb;
          float t = v*v;
          float m = fmaf(t, GB, GA);
          float e = __expf(v*m);
          HsNxt[(r0 + 4*lg + i)*40 + ct*16 + l15] = f2bf(v*__builtin_amdgcn_rcpf(1.f + e));
        }
      }
    }
    __syncthreads();   // frees used buffers; drains prefetches issued this iter
  }
  // ---- epilogue: out = bf16(x2) + fc2 + b2, single write ----
  #pragma unroll
  for (int ct2=0; ct2<12; ct2++) {
    int col = ct2*16+l15;
    float bb = b2[col];
    #pragma unroll
    for (int i=0;i<4;i++){
      float x2v = bf2f(AT[(rbase + r0 + 4*lg + i)*DIM + col]);
      out[(size_t)toks[i]*DIM + col] = x2v + acc2[ct2][i] + bb;
    }
  }
}

// ---------------- launcher ----------------
extern "C" void kernel_launch(void* const* d_in, const int* in_sizes, int n_in,
                              void* d_out, int out_size, void* d_ws, size_t ws_size,
                              hipStream_t stream) {
  const float* x    = (const float*)d_in[0];
  const float* n1g  = (const float*)d_in[1];
  const float* n1b  = (const float*)d_in[2];
  const float* qkvw = (const float*)d_in[3];
  const float* qkvb = (const float*)d_in[4];
  const float* eb   = (const float*)d_in[5];
  const float* projw= (const float*)d_in[6];
  const float* projb= (const float*)d_in[7];
  const float* n2g  = (const float*)d_in[8];
  const float* n2b  = (const float*)d_in[9];
  const float* fc1w = (const float*)d_in[10];
  const float* fc1b = (const float*)d_in[11];
  const float* fc2w = (const float*)d_in[12];
  const float* fc2b = (const float*)d_in[13];
  float* out = (float*)d_out;
  char* ws = (char*)d_ws;

  u16* AT  = (u16*)(ws + 53084160);      // 53,084,160 B  (attn out; then x2 bf16)
  u16* Wq  = (u16*)(ws + 106168320);     // qkv_w_t   221,184 B
  u16* Pw  = (u16*)(ws + 106389504);     // proj_w_t   73,728 B
  u16* W1f = (u16*)(ws + 106463232);     // fc1 frag-major 294,912 B
  u16* W2f = (u16*)(ws + 106758144);     // fc2 frag-major 294,912 B
  u16* Bexp = (u16*)d_out;               // 15.9 MB, dead once fused tail runs

  hipFuncSetAttribute((const void*)attn_kernel,       hipFuncAttributeMaxDynamicSharedMemorySize, SMEM3);
  hipFuncSetAttribute((const void*)fused_tail_kernel, hipFuncAttributeMaxDynamicSharedMemorySize, SMEMF);

  prep_kernel<<<1728, 256, 0, stream>>>(qkvw, Wq, projw, Pw, fc1w, W1f, fc2w, W2f);
  bias_expand_kernel<<<384, 256, 0, stream>>>(eb, Bexp);
  attn_kernel<<<5760, 576, SMEM3, stream>>>(x, n1g, n1b, Wq, qkvb, Bexp, AT);
  fused_tail_kernel<<<1080, 512, SMEMF, stream>>>(AT, Pw, projb, x, n2g, n2b,
                                                  W1f, fc1b, W2f, fc2b, out);
}

// Round 20
// 394.233 us; speedup vs baseline: 1.1004x; 1.1004x over previous
//
#include <hip/hip_runtime.h>
#include <hip/hip_bf16.h>
#include <math.h>

typedef unsigned short u16;
typedef __attribute__((ext_vector_type(8))) short short8;   // 8 bf16 MFMA A/B frag
typedef __attribute__((ext_vector_type(4))) short short4v;  // 4 bf16 packed
typedef __attribute__((ext_vector_type(4))) float f32x4;    // MFMA C/D frag

#define MFMA(a,b,c) __builtin_amdgcn_mfma_f32_16x16x32_bf16(a,b,c,0,0,0)
#define DIM 192

__device__ __forceinline__ float bf2f(u16 u){ unsigned v=((unsigned)u)<<16; float f; __builtin_memcpy(&f,&v,4); return f; }
__device__ __forceinline__ u16 f2bf(float f){ unsigned v; __builtin_memcpy(&v,&f,4); v = v + 0x7fffu + ((v>>16)&1u); return (u16)(v>>16); }

__device__ __forceinline__ void gl_lds16(const u16* g, u16* l){
  __builtin_amdgcn_global_load_lds((const __attribute__((address_space(1))) unsigned int*)g,
                                   (__attribute__((address_space(3))) unsigned int*)l, 16, 0, 0);
}

// windowed row -> original token index (inverse of roll(-1,-3,-6) + partition)
__device__ __forceinline__ int win_to_tok(int r){
  int lon = r/9216; int rem = r - lon*9216;      // 9216 = 64*144
  int w = rem/144, n = rem - w*144;
  int ip=w>>4, il=w&15;
  int wp=n/72, t=n-wp*72, wl=t/12, ww=t-wl*12;
  int p=ip*2+wp, la=il*6+wl, lo=lon*12+ww;
  int p0=p+1;  if(p0>=8)   p0-=8;
  int la0=la+3; if(la0>=96) la0-=96;
  int lo0=lo+6; if(lo0>=180)lo0-=180;
  return (p0*96+la0)*180+lo0;
}

// ---------------- K1: LN1 + roll + window partition -> bf16 A ----------------
__global__ __launch_bounds__(256) void ln1_window_kernel(
    const float* __restrict__ x, const float* __restrict__ g, const float* __restrict__ b,
    u16* __restrict__ A)
{
  int r = blockIdx.x*4 + (threadIdx.x>>6);
  int lane = threadIdx.x & 63;
  size_t src = (size_t)win_to_tok(r)*DIM;
  float v0=x[src+lane], v1=x[src+64+lane], v2=x[src+128+lane];
  float s=v0+v1+v2;
  for(int m=32;m>=1;m>>=1) s += __shfl_xor(s,m);
  float mean = s*(1.f/192.f);
  float d0=v0-mean,d1=v1-mean,d2=v2-mean;
  float q=d0*d0+d1*d1+d2*d2;
  for(int m=32;m>=1;m>>=1) q += __shfl_xor(q,m);
  float rstd = rsqrtf(q*(1.f/192.f)+1e-5f);
  size_t o = (size_t)r*DIM;
  A[o+lane]     = f2bf(d0*rstd*g[lane]     + b[lane]);
  A[o+64+lane]  = f2bf(d1*rstd*g[64+lane]  + b[64+lane]);
  A[o+128+lane] = f2bf(d2*rstd*g[128+lane] + b[128+lane]);
}

// ---------------- K2: merged preformat (4 ranged sub-kernels, one launch) ----------------
// blocks [0,432): qkv_w fp32[192][576] -> Wq bf16[576][192]
// blocks [432,576): proj_w fp32[192][192] -> Pw bf16[192][192]
// blocks [576,1152): fc1 -> W1f[hc 24][r 32][g 24][e 8], swizzle baked
// blocks [1152,1728): fc2 -> W2f[hc 24][r 192][g 4][e 8], swizzle baked
__global__ __launch_bounds__(256) void prep_kernel(
    const float* __restrict__ qkvw, u16* __restrict__ Wq,
    const float* __restrict__ projw, u16* __restrict__ Pw,
    const float* __restrict__ fc1w, u16* __restrict__ W1f,
    const float* __restrict__ fc2w, u16* __restrict__ W2f)
{
  int bid = blockIdx.x, tid = threadIdx.x;
  if (bid < 432) {
    int idx = bid*256 + tid;                    // 110592
    int k = idx / 576, n = idx - k*576;
    Wq[n*192 + k] = f2bf(qkvw[idx]);
  } else if (bid < 576) {
    int idx = (bid-432)*256 + tid;              // 36864
    int k = idx / 192, n = idx - k*192;
    Pw[n*192 + k] = f2bf(projw[idx]);
  } else if (bid < 1152) {
    int idx = (bid-576)*256 + tid;              // 147456
    int e = idx & 7, g3 = idx >> 3;
    int g = g3 % 24, r3 = g3 / 24;
    int r = r3 & 31, hc = r3 >> 5;
    int k = ((g ^ (r&7))<<3) + e;
    W1f[idx] = f2bf(fc1w[(size_t)k*768 + hc*32 + r]);
  } else {
    int idx = (bid-1152)*256 + tid;             // 147456
    int e = idx & 7, g3 = idx >> 3;
    int g = g3 & 3, r3 = g3 >> 2;
    int r = r3 % 192, hc = r3 / 192;
    int k = hc*32 + ((g ^ (r&3))<<3) + e;
    W2f[idx] = f2bf(fc2w[(size_t)k*192 + r]);
  }
}

// ---------------- K2c: expand earth bias+mask -> lane-packed Bexp ----------------
__global__ __launch_bounds__(256) void bias_expand_kernel(
    const float* __restrict__ eb, u16* __restrict__ B2)
{
  __shared__ int t1s[144], t2s[144], rgs[144];
  __shared__ float ebs[3312];
  int bid = blockIdx.x;           // bid = w*6 + h
  int w = bid / 6;
  int tid = threadIdx.x;
  if (tid < 144) {
    int n = tid;
    int wp=n/72, t=n-wp*72, wl=t/12, ww=t-wl*12;
    t1s[n] = wp*828 + wl*23 + ww;
    t2s[n] = 1656*wp + 138*wl - ww + 11;
    int ip = w>>4, il = w&15;
    int p = ip*2+wp, la = il*6+wl;
    int rp = (p<6)?0:((p<7)?1:2);
    int rl = (la<90)?0:((la<93)?1:2);
    rgs[n] = rp*3+rl;
  }
  for (int i = tid; i < 3312; i += 256) ebs[i] = eb[(size_t)i*384 + bid];
  __syncthreads();
  size_t ob = (size_t)bid*20736;
  for (int idx = tid; idx < 20736; idx += 256) {
    int i = idx & 3, lane = (idx>>2)&63, t = idx>>8;   // t = nt*9+mt
    int mt = t%9, nt = t/9;
    int n = nt*16 + (lane&15);
    int m = mt*16 + ((lane>>4)<<2) + i;
    float bv = ebs[t1s[n]+t2s[m]];
    bv += (rgs[n]==rgs[m]) ? 0.f : -100.f;
    B2[ob + idx] = f2bf(bv);
  }
}

// ---------------- K3: fused QKV + earth attention per (lon,w,head) ----------------
#define SM_WS   0                  // 36864 B  (96*192*2)
#define SM_QS   36864              // 11520 B  (144*40*2)
#define SM_KS   48384              // 11520 B
#define SM_VS   59904              // 10752 B  (32*168*2)
#define SM_PS   0                  // 48384 B  overlays Ws+qs (time-multiplexed)
#define SMEM3   70656              // 2 blocks/CU

__global__ __launch_bounds__(576) void attn_kernel(
    const u16* __restrict__ A,      // windowed bf16 [138240][192]
    const u16* __restrict__ Wt,     // qkv_w_t bf16 [576][192]
    const float* __restrict__ qkvb, // [576]
    const u16* __restrict__ Bexp,   // lane-packed [384][9][9][64][4] bf16
    u16* __restrict__ O)            // windowed attn out bf16 [138240][192]
{
  extern __shared__ char smem[];
  u16* Ws = (u16*)(smem + SM_WS);
  u16* qs = (u16*)(smem + SM_QS);
  u16* ks_= (u16*)(smem + SM_KS);
  u16* vs = (u16*)(smem + SM_VS);
  u16* Ps = (u16*)(smem + SM_PS);

  int bid = blockIdx.x;
  int logical = (bid & 7)*720 + (bid >> 3);     // bijective XCD remap
  int lon = logical % 15;
  int wh  = logical / 15;
  int h = wh % 6, w = wh / 6;
  int tid = threadIdx.x, lane = tid & 63, wv = tid >> 6;

  { // stage per-head weight slice into swizzled Ws (granule g^(row&7))
    int rr = tid % 96, chunk = tid / 96;
    int mat = rr >> 5, c = rr & 31;
    const u16* s = Wt + (size_t)(mat*192 + h*32 + c)*192 + chunk*32;
    uint4 t0 = *(const uint4*)(s);
    uint4 t1 = *(const uint4*)(s+8);
    uint4 t2 = *(const uint4*)(s+16);
    uint4 t3 = *(const uint4*)(s+24);
    u16* d = Ws + rr*192;
    int r7 = rr & 7, g0 = chunk*4;
    *(uint4*)(d + ((g0  )^r7)*8) = t0;
    *(uint4*)(d + ((g0+1)^r7)*8) = t1;
    *(uint4*)(d + ((g0+2)^r7)*8) = t2;
    *(uint4*)(d + ((g0+3)^r7)*8) = t3;
  }
  if (tid < 512) { int c = tid>>4; vs[c*168 + 144 + (tid&15)] = 0; }
  __syncthreads();

  size_t winbase = (size_t)(lon*64 + w)*144;
  int r0 = wv*16;
  int l15 = lane & 15, lg = lane >> 4;
  int sw7 = l15 & 7;

  short8 af[6];
  {
    const u16* arow = A + (winbase + r0 + l15)*DIM + 8*lg;
    #pragma unroll
    for (int k0=0;k0<6;k0++) af[k0] = *(const short8*)(arow + k0*32);
  }
  const float qscale = 0.17677669529663687f;

  #pragma unroll
  for (int mt=0; mt<2; mt++) {
    f32x4 acc = {0.f,0.f,0.f,0.f};
    const u16* wrow = Ws + (mt*16 + l15)*192;
    #pragma unroll
    for (int k0=0;k0<6;k0++) acc = MFMA(*(const short8*)(wrow + ((k0*4+lg)^sw7)*8), af[k0], acc);
    short4v pk;
    #pragma unroll
    for (int i=0;i<4;i++) pk[i] = (short)f2bf((acc[i] + qkvb[h*32 + mt*16 + 4*lg + i])*qscale);
    *(short4v*)(qs + (r0 + l15)*40 + mt*16 + 4*lg) = pk;
  }
  #pragma unroll
  for (int mt=0; mt<2; mt++) {
    f32x4 acc = {0.f,0.f,0.f,0.f};
    const u16* wrow = Ws + (32 + mt*16 + l15)*192;
    #pragma unroll
    for (int k0=0;k0<6;k0++) acc = MFMA(*(const short8*)(wrow + ((k0*4+lg)^sw7)*8), af[k0], acc);
    short4v pk;
    #pragma unroll
    for (int i=0;i<4;i++) pk[i] = (short)f2bf(acc[i] + qkvb[192 + h*32 + mt*16 + 4*lg + i]);
    *(short4v*)(ks_ + (r0 + l15)*40 + mt*16 + 4*lg) = pk;
  }
  #pragma unroll
  for (int ct=0; ct<2; ct++) {
    f32x4 acc = {0.f,0.f,0.f,0.f};
    const u16* wrow = Ws + (64 + ct*16 + l15)*192;
    #pragma unroll
    for (int k0=0;k0<6;k0++) acc = MFMA(af[k0], *(const short8*)(wrow + ((k0*4+lg)^sw7)*8), acc);
    float bias = qkvb[384 + h*32 + ct*16 + l15];
    short4v pk;
    #pragma unroll
    for (int i=0;i<4;i++) pk[i] = (short)f2bf(acc[i] + bias);
    *(short4v*)(vs + (ct*16 + l15)*168 + r0 + 4*lg) = pk;
  }
  __syncthreads();

  short8 bq = *(const short8*)(qs + (r0 + l15)*40 + 8*lg);
  f32x4 sa[9];
  #pragma unroll
  for (int mt=0; mt<9; mt++) {
    f32x4 z = {0.f,0.f,0.f,0.f};
    sa[mt] = MFMA(*(const short8*)(ks_ + (mt*16 + l15)*40 + 8*lg), bq, z);
  }
  __syncthreads();

  {
    const u16* bb = Bexp + (((size_t)wh*9 + wv)*9)*256 + lane*4;
    #pragma unroll
    for (int mt=0; mt<9; mt++) {
      short4v pk = *(const short4v*)(bb + mt*256);
      #pragma unroll
      for (int i=0;i<4;i++) sa[mt][i] += bf2f((u16)pk[i]);
    }
  }
  float rsum = 0.f;
  #pragma unroll
  for (int mt=0; mt<9; mt++)
    #pragma unroll
    for (int i=0;i<4;i++) { float e = __expf(sa[mt][i]); sa[mt][i] = e; rsum += e; }
  rsum += __shfl_xor(rsum, 16);
  rsum += __shfl_xor(rsum, 32);
  float rinv = 1.f / rsum;
  #pragma unroll
  for (int mt=0; mt<9; mt++) {
    short4v pk;
    #pragma unroll
    for (int i=0;i<4;i++) pk[i] = (short)f2bf(sa[mt][i]);
    *(short4v*)(Ps + (r0 + l15)*168 + mt*16 + 4*lg) = pk;
  }
  {
    short4v z = {0,0,0,0};
    *(short4v*)(Ps + (r0 + l15)*168 + 144 + 4*lg) = z;
  }

  #pragma unroll
  for (int ct2=0; ct2<2; ct2++) {
    f32x4 acc = {0.f,0.f,0.f,0.f};
    const u16* vr = vs + (ct2*16 + l15)*168 + 8*lg;
    const u16* pr = Ps + (r0 + l15)*168 + 8*lg;
    #pragma unroll
    for (int k0=0;k0<5;k0++) acc = MFMA(*(const short8*)(vr + 32*k0), *(const short8*)(pr + 32*k0), acc);
    short4v pk;
    #pragma unroll
    for (int i=0;i<4;i++) pk[i] = (short)f2bf(acc[i]*rinv);
    *(short4v*)(O + (winbase + r0 + l15)*DIM + h*32 + ct2*16 + 4*lg) = pk;
  }
}

// ---------------- K4: fused tail (R14 config) -- proj+LN2+MLP, fc1/fc2 pipelined ----------
#define SMEMF 74240
__global__ __launch_bounds__(512, 4) void fused_tail_kernel(
    u16* __restrict__ AT,          // in: attn out (windowed); scratch: x2 bf16
    const u16* __restrict__ Pw,    // proj_w_t bf16 [192][192]
    const float* __restrict__ pb, const float* __restrict__ x,
    const float* __restrict__ n2g, const float* __restrict__ n2b,
    const u16* __restrict__ W1f,  // [24][32][24][8]
    const float* __restrict__ b1,
    const u16* __restrict__ W2f,  // [24][192][4][8]
    const float* __restrict__ b2,
    float* __restrict__ out)
{
  extern __shared__ char smem[];
  u16* Pws  = (u16*)smem;                 // proj phase
  u16* Ys   = (u16*)smem;                 // handoff phase (overlay)
  u16* W1b0 = (u16*)smem;                 // mlp phase (overlay)
  u16* W1b1 = (u16*)(smem + 12288);
  u16* W2b0 = (u16*)(smem + 24576);
  u16* W2b1 = (u16*)(smem + 36864);
  u16* HsA  = (u16*)(smem + 49152);
  u16* HsB  = (u16*)(smem + 59392);
  int* tokmap = (int*)(smem + 73728);
  int tid = threadIdx.x;
  size_t rbase = (size_t)blockIdx.x*128;
  int lane = tid&63, wv = tid>>6, r0 = wv*16;
  int l15 = lane&15, lg = lane>>4;

  // ---- stage proj weights (swizzled) + tokmap ----
  #pragma unroll
  for (int j=0;j<9;j++){
    int g = j*512 + tid;
    int row = g/24, jj = g - row*24;
    uint4 t = *(const uint4*)(Pw + (size_t)row*192 + jj*8);
    *(uint4*)(Pws + row*192 + ((jj ^ (row&7))*8)) = t;
  }
  if (tid < 128) tokmap[tid] = win_to_tok((int)rbase + tid);
  __syncthreads();

  // ---- proj MFMA ----
  short8 af[6];
  {
    const u16* arow = AT + (rbase + r0 + l15)*DIM + 8*lg;
    #pragma unroll
    for (int k0=0;k0<6;k0++) af[k0] = *(const short8*)(arow + k0*32);
  }
  f32x4 acc[12];
  #pragma unroll
  for (int ct=0; ct<12; ct++) {
    f32x4 a = {0.f,0.f,0.f,0.f};
    const u16* wr = Pws + (ct*16+l15)*192;
    #pragma unroll
    for (int k0=0;k0<6;k0++) a = MFMA(af[k0], *(const short8*)(wr + (((k0*4+lg)^(l15&7))*8)), a);
    acc[ct] = a;
  }
  int toks[4];
  #pragma unroll
  for (int i=0;i<4;i++) toks[i] = tokmap[r0 + 4*lg + i];

  // ---- x2 = x + proj + pb; park bf16 in AT ----
  #pragma unroll
  for (int ct=0; ct<12; ct++) {
    int col = ct*16+l15;
    float bias = pb[col];
    #pragma unroll
    for (int i=0;i<4;i++){
      float v = x[(size_t)toks[i]*DIM + col] + acc[ct][i] + bias;
      acc[ct][i] = v;
      AT[(rbase + r0 + 4*lg + i)*DIM + col] = f2bf(v);
    }
  }
  // ---- LN2 ----
  float s[4] = {0,0,0,0};
  #pragma unroll
  for (int ct=0; ct<12; ct++) for (int i=0;i<4;i++) s[i] += acc[ct][i];
  #pragma unroll
  for (int i=0;i<4;i++){ for (int m=1;m<16;m<<=1) s[i] += __shfl_xor(s[i], m, 16); s[i] *= (1.f/192.f); }
  float q[4] = {0,0,0,0};
  #pragma unroll
  for (int ct=0; ct<12; ct++) for (int i=0;i<4;i++){ float d = acc[ct][i]-s[i]; q[i] += d*d; }
  #pragma unroll
  for (int i=0;i<4;i++){ for (int m=1;m<16;m<<=1) q[i] += __shfl_xor(q[i], m, 16); q[i] = rsqrtf(q[i]*(1.f/192.f)+1e-5f); }

  __syncthreads();    // all Pws reads done -> Ys overlay safe
  #pragma unroll
  for (int ct=0; ct<12; ct++) {
    int col = ct*16+l15;
    float gg = n2g[col], bb = n2b[col];
    #pragma unroll
    for (int i=0;i<4;i++)
      Ys[(r0 + 4*lg + i)*200 + col] = f2bf((acc[ct][i]-s[i])*q[i]*gg + bb);
  }
  #pragma unroll
  for (int k0=0;k0<6;k0++) af[k0] = *(const short8*)(Ys + (r0+l15)*200 + k0*32 + 8*lg);
  __syncthreads();    // all Ys reads done -> ring overlay safe

  // ---- stage W1(0), W2(0), W1(1) ----
  {
    gl_lds16(W1f + (size_t)tid*8, W1b0 + tid*8);
    if (tid < 256) gl_lds16(W1f + (size_t)(512+tid)*8, W1b0 + (512+tid)*8);
    gl_lds16(W2f + (size_t)tid*8, W2b0 + tid*8);
    if (tid < 256) gl_lds16(W2f + (size_t)(512+tid)*8, W2b0 + (512+tid)*8);
    const u16* s1 = W1f + 6144;
    gl_lds16(s1 + (size_t)tid*8, W1b1 + tid*8);
    if (tid < 256) gl_lds16(s1 + (size_t)(512+tid)*8, W1b1 + (512+tid)*8);
  }
  __syncthreads();

  f32x4 acc2[12];
  #pragma unroll
  for (int i=0;i<12;i++) acc2[i] = (f32x4){0.f,0.f,0.f,0.f};

  const float GA = -1.5957691216057307f;   // -2*0.7978845608
  const float GB = -0.07135481627272283f;  // -2*0.0356774081

  // prologue compute: fc1(0) -> HsA
  #pragma unroll
  for (int ct=0; ct<2; ct++) {
    f32x4 a1 = {0.f,0.f,0.f,0.f};
    const u16* wr = W1b0 + (ct*16+l15)*192;
    #pragma unroll
    for (int k0=0;k0<6;k0++) a1 = MFMA(af[k0], *(const short8*)(wr + (((k0*4+lg)^(l15&7))*8)), a1);
    float bb = b1[ct*16 + l15];
    #pragma unroll
    for (int i=0;i<4;i++){
      float v = a1[i] + bb;
      float t = v*v;
      float m = fmaf(t, GB, GA);
      float e = __expf(v*m);
      HsA[(r0 + 4*lg + i)*40 + ct*16 + l15] = f2bf(v*__builtin_amdgcn_rcpf(1.f + e));
    }
  }
  __syncthreads();    // all waves past fc1(0): W1b0 free for restage

  for (int hc=0; hc<24; hc++) {
    u16* HsCur = (hc&1) ? HsB : HsA;
    u16* HsNxt = (hc&1) ? HsA : HsB;
    u16* W2cur = (hc&1) ? W2b1 : W2b0;
    u16* W1nxt = (hc&1) ? W1b0 : W1b1;
    // issue prefetches into buffers freed by the previous barrier
    if (hc+2 < 24) {
      const u16* s1 = W1f + (size_t)(hc+2)*6144;
      u16* d1 = (hc&1) ? W1b1 : W1b0;
      gl_lds16(s1 + (size_t)tid*8, d1 + tid*8);
      if (tid < 256) gl_lds16(s1 + (size_t)(512+tid)*8, d1 + (512+tid)*8);
    }
    if (hc+1 < 24) {
      const u16* s2 = W2f + (size_t)(hc+1)*6144;
      u16* d2 = (hc&1) ? W2b0 : W2b1;
      gl_lds16(s2 + (size_t)tid*8, d2 + tid*8);
      if (tid < 256) gl_lds16(s2 + (size_t)(512+tid)*8, d2 + (512+tid)*8);
    }
    // fc2(hc): A = HsCur own rows, B = W2cur
    {
      short8 ah = *(const short8*)(HsCur + (r0+l15)*40 + 8*lg);
      #pragma unroll
      for (int ct2=0; ct2<12; ct2++) {
        const u16* wr2 = W2cur + (ct2*16+l15)*32 + ((lg ^ (l15&3))*8);
        acc2[ct2] = MFMA(ah, *(const short8*)(wr2), acc2[ct2]);
      }
    }
    // fc1(hc+1): B = W1nxt -> HsNxt (wave-private rows)
    if (hc+1 < 24) {
      #pragma unroll
      for (int ct=0; ct<2; ct++) {
        f32x4 a1 = {0.f,0.f,0.f,0.f};
        const u16* wr = W1nxt + (ct*16+l15)*192;
        #pragma unroll
        for (int k0=0;k0<6;k0++) a1 = MFMA(af[k0], *(const short8*)(wr + (((k0*4+lg)^(l15&7))*8)), a1);
        float bb = b1[(hc+1)*32 + ct*16 + l15];
        #pragma unroll
        for (int i=0;i<4;i++){
          float v = a1[i] + bb;
          float t = v*v;
          float m = fmaf(t, GB, GA);
          float e = __expf(v*m);
          HsNxt[(r0 + 4*lg + i)*40 + ct*16 + l15] = f2bf(v*__builtin_amdgcn_rcpf(1.f + e));
        }
      }
    }
    __syncthreads();   // frees used buffers; drains prefetches issued this iter
  }
  // ---- epilogue: out = bf16(x2) + fc2 + b2, single write ----
  #pragma unroll
  for (int ct2=0; ct2<12; ct2++) {
    int col = ct2*16+l15;
    float bb = b2[col];
    #pragma unroll
    for (int i=0;i<4;i++){
      float x2v = bf2f(AT[(rbase + r0 + 4*lg + i)*DIM + col]);
      out[(size_t)toks[i]*DIM + col] = x2v + acc2[ct2][i] + bb;
    }
  }
}

// ---------------- launcher ----------------
extern "C" void kernel_launch(void* const* d_in, const int* in_sizes, int n_in,
                              void* d_out, int out_size, void* d_ws, size_t ws_size,
                              hipStream_t stream) {
  const float* x    = (const float*)d_in[0];
  const float* n1g  = (const float*)d_in[1];
  const float* n1b  = (const float*)d_in[2];
  const float* qkvw = (const float*)d_in[3];
  const float* qkvb = (const float*)d_in[4];
  const float* eb   = (const float*)d_in[5];
  const float* projw= (const float*)d_in[6];
  const float* projb= (const float*)d_in[7];
  const float* n2g  = (const float*)d_in[8];
  const float* n2b  = (const float*)d_in[9];
  const float* fc1w = (const float*)d_in[10];
  const float* fc1b = (const float*)d_in[11];
  const float* fc2w = (const float*)d_in[12];
  const float* fc2b = (const float*)d_in[13];
  float* out = (float*)d_out;
  char* ws = (char*)d_ws;

  u16* A   = (u16*)(ws);                 // 53,084,160 B  (LN1 out)
  u16* AT  = (u16*)(ws + 53084160);      // 53,084,160 B  (attn out; then x2 bf16)
  u16* Wq  = (u16*)(ws + 106168320);     // qkv_w_t   221,184 B
  u16* Pw  = (u16*)(ws + 106389504);     // proj_w_t   73,728 B
  u16* W1f = (u16*)(ws + 106463232);     // fc1 frag-major 294,912 B
  u16* W2f = (u16*)(ws + 106758144);     // fc2 frag-major 294,912 B
  u16* Bexp = (u16*)d_out;               // 15.9 MB, dead once fused tail runs

  hipFuncSetAttribute((const void*)attn_kernel,       hipFuncAttributeMaxDynamicSharedMemorySize, SMEM3);
  hipFuncSetAttribute((const void*)fused_tail_kernel, hipFuncAttributeMaxDynamicSharedMemorySize, SMEMF);

  prep_kernel<<<1728, 256, 0, stream>>>(qkvw, Wq, projw, Pw, fc1w, W1f, fc2w, W2f);
  bias_expand_kernel<<<384, 256, 0, stream>>>(eb, Bexp);
  ln1_window_kernel<<<34560, 256, 0, stream>>>(x, n1g, n1b, A);
  attn_kernel<<<5760, 576, SMEM3, stream>>>(A, Wq, qkvb, Bexp, AT);
  fused_tail_kernel<<<1080, 512, SMEMF, stream>>>(AT, Pw, projb, x, n2g, n2b,
                                                  W1f, fc1b, W2f, fc2b, out);
}